// Round 4
// baseline (676.118 us; speedup 1.0000x reference)
//
#include <hip/hip_runtime.h>
#include <hip/hip_cooperative_groups.h>
#include <math.h>

namespace cg = cooperative_groups;

#define NN 15          // nodes
#define EMBED 2048
#define F1D 1024
#define F2D 512
#define NE 120         // edges
#define H1_DIM 480
#define H2_DIM 1920
#define H3_DIM 30720   // 15*2048

// workspace layout (float offsets) — no zero-init needed anywhere
#define OFF_A    0         // 225 (pad 256)
#define OFF_H2   256       // 1920 (pad 2048) -> 2304
#define OFF_P3   2304      // 16*30720 = 491520 -> 493824   (k2 K-split partials)
#define OFF_XG1  493824    // 15*2048 = 30720 -> 524544     (A_hat @ h3)
#define OFF_P1   524544    // 32*15*1024 = 491520 -> 1016064
#define OFF_XG2  1016064   // 15*1024 = 15360 -> 1031424    (A_hat @ relu(...))
#define OFF_P2   1031424   // 16*15*512 = 122880 -> 1154304
#define OFF_X2   1154304   // 15*512 = 7680 -> 1161984
#define OFF_XBAR 1161984   // 512 -> 1162496
#define OFF_CTX  1162496   // 512 -> 1163008

typedef float vf4 __attribute__((ext_vector_type(4)));

__device__ inline void f4ma(float4& a, float s, const float4& w) {
    a.x += s * w.x; a.y += s * w.y; a.z += s * w.z; a.w += s * w.w;
}
__device__ inline void f4acc(float4& a, const float4& b) {
    a.x += b.x; a.y += b.y; a.z += b.z; a.w += b.w;
}

// ---------------- K1: blocks 0..59: h1 = relu(f@W1+b1), h2 slice; block 60: A_hat ----------------
__global__ void k1_h2(const float* __restrict__ f, const float* __restrict__ W1,
                      const float* __restrict__ b1, const float* __restrict__ W2,
                      const float* __restrict__ b2, const int* __restrict__ edges,
                      float* __restrict__ ws) {
    int tid = threadIdx.x;
    if (blockIdx.x == 60) {
        __shared__ float dinv[NN];
        __shared__ float A[NN * NN];
        if (tid < NN) {
            int deg = 1;  // self loop
            for (int i = 0; i < NE; ++i) deg += (edges[NE + i] == tid) ? 1 : 0;
            dinv[tid] = rsqrtf((float)deg);
        }
        __syncthreads();
        if (tid < NN * NN) {
            int r = tid / NN, c = tid % NN;
            A[tid] = (r == c) ? dinv[r] * dinv[r] : 0.0f;
        }
        __syncthreads();
        if (tid == 0) {
            for (int i = 0; i < NE; ++i) {
                int s = edges[i], d = edges[NE + i];
                A[d * NN + s] += dinv[s] * dinv[d];
            }
        }
        __syncthreads();
        if (tid < NN * NN) ws[OFF_A + tid] = A[tid];
        return;
    }
    __shared__ float h1[H1_DIM];
    __shared__ float4 red[32][8];
    float fr[NN];
#pragma unroll
    for (int k = 0; k < NN; ++k) fr[k] = f[k];
    for (int j = tid; j < H1_DIM; j += 256) {
        float acc = b1[j];
#pragma unroll
        for (int k = 0; k < NN; ++k) acc += fr[k] * W1[k * H1_DIM + j];
        h1[j] = fmaxf(acc, 0.0f);
    }
    __syncthreads();
    int jg = tid & 7, kc = tid >> 3;
    int j = blockIdx.x * 32 + jg * 4;
    float4 acc = make_float4(0.f, 0.f, 0.f, 0.f);
    for (int r = 0; r < 15; ++r) {
        int k = kc * 15 + r;
        float4 w = *(const float4*)(W2 + k * H2_DIM + j);
        f4ma(acc, h1[k], w);
    }
    red[kc][jg] = acc;
    __syncthreads();
    for (int s = 16; s >= 1; s >>= 1) {
        if (kc < s) f4acc(red[kc][jg], red[kc + s][jg]);
        __syncthreads();
    }
    if (kc == 0) {
        float4 b = *(const float4*)(b2 + j);
        float4 v = red[0][jg];
        v.x = fmaxf(v.x + b.x, 0.f); v.y = fmaxf(v.y + b.y, 0.f);
        v.z = fmaxf(v.z + b.z, 0.f); v.w = fmaxf(v.w + b.w, 0.f);
        *(float4*)(ws + OFF_H2 + j) = v;
    }
}

// ---------------- K2: h3 partials = h2 @ W3 (~118 MB stream via relu-zero row skip) ----------------
// grid (32 col-blocks of 960, 16 k-chunks of 120 rows) = 512 blocks = EXACTLY 2/CU
__global__ void k2_h3(const float* __restrict__ W3, float* __restrict__ ws) {
    __shared__ float cval[120];
    __shared__ int   coff[120];
    __shared__ int   wcnt[2];
    int tid = threadIdx.x;
    int cb = blockIdx.x, kc = blockIdx.y;
    int kbase = kc * 120;
    float hv = 0.0f;
    if (tid < 120) hv = ws[OFF_H2 + kbase + tid];
    int lane = tid & 63, wv = tid >> 6;
    bool act = (tid < 120) && (hv != 0.0f);
    unsigned long long m = __ballot(act);
    if (wv < 2 && lane == 0) wcnt[wv] = __popcll(m);
    __syncthreads();
    if (act) {
        int off = (wv == 1) ? wcnt[0] : 0;
        int p = off + __popcll(m & ((1ull << lane) - 1ull));
        coff[p] = (kbase + tid) * H3_DIM;
        cval[p] = hv;
    }
    __syncthreads();
    int nr = wcnt[0] + wcnt[1];
    if (tid >= 240) return;
    int col = cb * 960 + tid * 4;
    float4 acc = make_float4(0.f, 0.f, 0.f, 0.f);
#pragma unroll 8
    for (int r = 0; r < nr; ++r) {
        vf4 w = __builtin_nontemporal_load((const vf4*)(W3 + (size_t)coff[r] + col));
        float s = cval[r];
        acc.x += s * w.x; acc.y += s * w.y; acc.z += s * w.z; acc.w += s * w.w;
    }
    *(float4*)(ws + OFF_P3 + (size_t)kc * H3_DIM + col) = acc;
}

// ---------------- K_TAIL: cooperative fusion of old k3..k9 (7 launches -> 1) ----------------
// grid 256 blocks x 256 threads; 6 grid.sync()s. Per-stage parallelism kept >= old per-kernel.
__global__ void __launch_bounds__(256, 1)
k_tail(const float* __restrict__ b3, const float* __restrict__ gW1,
       const float* __restrict__ gb1, const float* __restrict__ gW2,
       const float* __restrict__ gb2, const float* __restrict__ attW,
       const float* __restrict__ fcW, const float* __restrict__ fcb,
       const float* __restrict__ target, float* __restrict__ ws,
       float* __restrict__ out) {
    cg::grid_group grid = cg::this_grid();
    __shared__ float4 red4[8][32][NN];          // 61440 B (scratch alias Sf for small stages)
    __shared__ float Xl[NN * 64];               // 3840 B
    __shared__ float Al[240];                   // A_hat (225, padded)
    float* Sf = (float*)red4;
    int tid = threadIdx.x;
    int b = blockIdx.x;

    for (int i = tid; i < NN * NN; i += 256) Al[i] = ws[OFF_A + i];

    // ---- stage A (old k3): h3 = sum16 P3 + b3; XG1 = A_hat @ h3. 8 cols/block ----
    {
        int c0 = b * 8;
        if (tid < 120) {
            int mm = tid >> 3, c = tid & 7;
            int j = mm * EMBED + c0 + c;
            float s = b3[j];
#pragma unroll
            for (int p = 0; p < 16; ++p) s += ws[OFF_P3 + p * H3_DIM + j];
            Sf[mm * 8 + c] = s;
        }
        __syncthreads();
        if (tid < 120) {
            int n = tid >> 3, c = tid & 7;
            float x = 0.f;
#pragma unroll
            for (int mm = 0; mm < NN; ++mm) x += Al[n * NN + mm] * Sf[mm * 8 + c];
            ws[OFF_XG1 + n * EMBED + c0 + c] = x;
        }
    }
    __threadfence();
    grid.sync();

    // ---- stage B (old k4): XG1[15,2048] @ gW1[2048,1024] -> P1[32][15][1024] ----
    // 8 f-blocks x 32 e-chunks of 64
    {
        int e0 = (b & 31) * 64;
        for (int i = tid; i < NN * 64; i += 256) {
            int n = i >> 6, e = i & 63;
            Xl[i] = ws[OFF_XG1 + n * EMBED + e0 + e];
        }
        __syncthreads();
        int fg = tid & 31, kt = tid >> 5;
        int fcol = (b >> 5) * 128 + fg * 4;
        float4 acc[NN];
#pragma unroll
        for (int n = 0; n < NN; ++n) acc[n] = make_float4(0.f, 0.f, 0.f, 0.f);
        for (int r = 0; r < 8; ++r) {
            int e = kt * 8 + r;
            float4 w = *(const float4*)(gW1 + (size_t)(e0 + e) * F1D + fcol);
#pragma unroll
            for (int n = 0; n < NN; ++n) f4ma(acc[n], Xl[n * 64 + e], w);
        }
        __syncthreads();
#pragma unroll
        for (int n = 0; n < NN; ++n) red4[kt][fg][n] = acc[n];
        __syncthreads();
        for (int s = 4; s >= 1; s >>= 1) {
            if (kt < s) {
#pragma unroll
                for (int n = 0; n < NN; ++n) f4acc(red4[kt][fg][n], red4[kt + s][fg][n]);
            }
            __syncthreads();
        }
        if (kt == 0) {
#pragma unroll
            for (int n = 0; n < NN; ++n)
                *(float4*)(ws + OFF_P1 + (size_t)(b & 31) * (NN * F1D) + n * F1D + fcol) = red4[0][fg][n];
        }
    }
    __threadfence();
    grid.sync();

    // ---- stage C (old k5): X1 = relu(sum32 P1 + gb1); XG2 = A_hat @ X1. 4 cols/block ----
    {
        int c0 = b * 4;
        if (tid < 60) {
            int mm = tid >> 2, c = tid & 3;
            float s = gb1[c0 + c];
#pragma unroll
            for (int p = 0; p < 32; ++p) s += ws[OFF_P1 + p * (NN * F1D) + mm * F1D + c0 + c];
            Sf[mm * 4 + c] = fmaxf(s, 0.f);
        }
        __syncthreads();
        if (tid < 60) {
            int n = tid >> 2, c = tid & 3;
            float x = 0.f;
#pragma unroll
            for (int mm = 0; mm < NN; ++mm) x += Al[n * NN + mm] * Sf[mm * 4 + c];
            ws[OFF_XG2 + n * F1D + c0 + c] = x;
        }
    }
    __threadfence();
    grid.sync();

    // ---- stage D (old k6): XG2[15,1024] @ gW2[1024,512] -> P2[16][15][512] ----
    // blocks 0..63 active: 4 f-blocks x 16 e-chunks of 64
    if (b < 64) {
        int e0 = (b & 15) * 64;
        for (int i = tid; i < NN * 64; i += 256) {
            int n = i >> 6, e = i & 63;
            Xl[i] = ws[OFF_XG2 + n * F1D + e0 + e];
        }
        __syncthreads();
        int fg = tid & 31, kt = tid >> 5;
        int fcol = (b >> 4) * 128 + fg * 4;
        float4 acc[NN];
#pragma unroll
        for (int n = 0; n < NN; ++n) acc[n] = make_float4(0.f, 0.f, 0.f, 0.f);
        for (int r = 0; r < 8; ++r) {
            int e = kt * 8 + r;
            float4 w = *(const float4*)(gW2 + (size_t)(e0 + e) * F2D + fcol);
#pragma unroll
            for (int n = 0; n < NN; ++n) f4ma(acc[n], Xl[n * 64 + e], w);
        }
        __syncthreads();
#pragma unroll
        for (int n = 0; n < NN; ++n) red4[kt][fg][n] = acc[n];
        __syncthreads();
        for (int s = 4; s >= 1; s >>= 1) {
            if (kt < s) {
#pragma unroll
                for (int n = 0; n < NN; ++n) f4acc(red4[kt][fg][n], red4[kt + s][fg][n]);
            }
            __syncthreads();
        }
        if (kt == 0) {
#pragma unroll
            for (int n = 0; n < NN; ++n)
                *(float4*)(ws + OFF_P2 + (size_t)(b & 15) * (NN * F2D) + n * F2D + fcol) = red4[0][fg][n];
        }
    }
    __threadfence();
    grid.sync();

    // ---- stage E (old k7): X2 = sum16 P2 + gb2; xbar = mean_n X2. 2 cols/block ----
    {
        int c0 = b * 2;
        if (tid < 30) {
            int mm = tid >> 1, c = tid & 1;
            float s = gb2[c0 + c];
#pragma unroll
            for (int p = 0; p < 16; ++p) s += ws[OFF_P2 + p * (NN * F2D) + mm * F2D + c0 + c];
            ws[OFF_X2 + mm * F2D + c0 + c] = s;
            Sf[tid] = s;
        }
        __syncthreads();
        if (tid < 2) {
            float s = 0.f;
#pragma unroll
            for (int n = 0; n < NN; ++n) s += Sf[n * 2 + tid];
            ws[OFF_XBAR + c0 + tid] = s * (1.0f / 15.0f);
        }
    }
    __threadfence();
    grid.sync();

    // ---- stage F (old k8): ctx = tanh(xbar @ attW). blocks 0..31, 16 outputs each ----
    if (b < 32) {
        float* xb = Sf;                          // 512 floats
        float4* redc = (float4*)(Sf + 512);      // [64][4]
        for (int e = tid; e < F2D; e += 256) xb[e] = ws[OFF_XBAR + e];
        __syncthreads();
        int fg = tid & 3, kt = tid >> 2;
        int fcol = b * 16 + fg * 4;
        float4 acc = make_float4(0.f, 0.f, 0.f, 0.f);
        for (int r = 0; r < 8; ++r) {
            int e = kt * 8 + r;
            float4 w = *(const float4*)(attW + e * F2D + fcol);
            f4ma(acc, xb[e], w);
        }
        redc[kt * 4 + fg] = acc;
        __syncthreads();
        for (int s = 32; s >= 1; s >>= 1) {
            if (kt < s) f4acc(redc[kt * 4 + fg], redc[(kt + s) * 4 + fg]);
            __syncthreads();
        }
        if (kt == 0) {
            float4 v = redc[fg];
            ws[OFF_CTX + fcol + 0] = tanhf(v.x);
            ws[OFF_CTX + fcol + 1] = tanhf(v.y);
            ws[OFF_CTX + fcol + 2] = tanhf(v.z);
            ws[OFF_CTX + fcol + 3] = tanhf(v.w);
        }
    }
    __threadfence();
    grid.sync();

    // ---- stage G (old k9): scores, rep, logits, loss. block 0 only ----
    if (b != 0) return;
    {
        float* x2l   = Sf;                       // 7680
        float* ctxl  = Sf + 7680;                // 512
        float* scores= Sf + 8192;                // 16
        float* rep   = Sf + 8208;                // 512
        float* logit = Sf + 8720;                // 3
        for (int i = tid; i < NN * F2D; i += 256) x2l[i] = ws[OFF_X2 + i];
        for (int i = tid; i < F2D; i += 256) ctxl[i] = ws[OFF_CTX + i];
        __syncthreads();
        {
            int g = tid >> 4, l = tid & 15;
            if (g < NN) {
                float p = 0.f;
                for (int i = 0; i < 32; ++i) {
                    int e = l + 16 * i;
                    p += x2l[g * F2D + e] * ctxl[e];
                }
                p += __shfl_xor(p, 1); p += __shfl_xor(p, 2);
                p += __shfl_xor(p, 4); p += __shfl_xor(p, 8);
                if (l == 0) scores[g] = 1.0f / (1.0f + expf(-p));
            }
        }
        __syncthreads();
        for (int fi = tid; fi < F2D; fi += 256) {
            float v = 0.f;
#pragma unroll
            for (int n = 0; n < NN; ++n) v += x2l[n * F2D + fi] * scores[n];
            rep[fi] = v;
        }
        __syncthreads();
        if (tid < 192) {
            int j = tid >> 6, l = tid & 63;
            float p = 0.f;
            for (int i = 0; i < 8; ++i) {
                int e = l + 64 * i;
                p += rep[e] * fcW[e * 3 + j];
            }
            p += __shfl_xor(p, 1); p += __shfl_xor(p, 2); p += __shfl_xor(p, 4);
            p += __shfl_xor(p, 8); p += __shfl_xor(p, 16); p += __shfl_xor(p, 32);
            if (l == 0) logit[j] = p + fcb[j];
        }
        __syncthreads();
        if (tid == 0) {
            float t0 = target[0], t1 = target[1], t2 = target[2];
            int cls = 0; float best = t0;
            if (t1 > best) { best = t1; cls = 1; }
            if (t2 > best) { cls = 2; }
            float l0 = logit[0], l1 = logit[1], l2 = logit[2];
            float mx = fmaxf(l0, fmaxf(l1, l2));
            float e0 = expf(l0 - mx), e1 = expf(l1 - mx), e2 = expf(l2 - mx);
            float s = e0 + e1 + e2;
            float lc = (cls == 0) ? l0 : ((cls == 1) ? l1 : l2);
            out[0] = -(lc - mx - logf(s));
            out[1] = e0 / s; out[2] = e1 / s; out[3] = e2 / s;
        }
    }
}

extern "C" void kernel_launch(void* const* d_in, const int* in_sizes, int n_in,
                              void* d_out, int out_size, void* d_ws, size_t ws_size,
                              hipStream_t stream) {
    const float* f    = (const float*)d_in[0];
    const int*   ei   = (const int*)d_in[1];
    const float* tgt  = (const float*)d_in[2];
    const float* W1   = (const float*)d_in[3];
    const float* b1   = (const float*)d_in[4];
    const float* W2   = (const float*)d_in[5];
    const float* b2   = (const float*)d_in[6];
    const float* W3   = (const float*)d_in[7];
    const float* b3   = (const float*)d_in[8];
    const float* gW1  = (const float*)d_in[9];
    const float* gb1  = (const float*)d_in[10];
    const float* gW2  = (const float*)d_in[11];
    const float* gb2  = (const float*)d_in[12];
    const float* attW = (const float*)d_in[13];
    const float* fcW  = (const float*)d_in[14];
    const float* fcb  = (const float*)d_in[15];
    float* ws  = (float*)d_ws;
    float* out = (float*)d_out;

    k1_h2<<<dim3(61), dim3(256), 0, stream>>>(f, W1, b1, W2, b2, ei, ws);
    k2_h3<<<dim3(32, 16), dim3(256), 0, stream>>>(W3, ws);

    void* args[] = {(void*)&b3, (void*)&gW1, (void*)&gb1, (void*)&gW2, (void*)&gb2,
                    (void*)&attW, (void*)&fcW, (void*)&fcb, (void*)&tgt,
                    (void*)&ws, (void*)&out};
    hipLaunchCooperativeKernel((const void*)k_tail, dim3(256), dim3(256), args, 0, stream);
}

// Round 5
// 380.337 us; speedup vs baseline: 1.7777x; 1.7777x over previous
//
#include <hip/hip_runtime.h>
#include <math.h>

#define NN 15          // nodes
#define EMBED 2048
#define F1D 1024
#define F2D 512
#define NE 120         // edges
#define H1_DIM 480
#define H2_DIM 1920
#define H3_DIM 30720   // 15*2048

// workspace layout (float offsets) — no zero-init needed anywhere
#define OFF_A    0         // 225 (pad 256)
#define OFF_H2   256       // 1920 (pad 2048) -> 2304
#define OFF_P3   2304      // 16*30720 = 491520 -> 493824   (k2 K-split partials)
#define OFF_P1   493824    // 16*15*1024 = 245760 -> 739584
#define OFF_P2   739584    // 16*15*512 = 122880 -> 862464
#define OFF_X2   862464    // 15*512 = 7680 -> 870144
#define OFF_CTX  870144    // 512 -> 870656

typedef float vf4 __attribute__((ext_vector_type(4)));

__device__ inline void f4ma(float4& a, float s, const float4& w) {
    a.x += s * w.x; a.y += s * w.y; a.z += s * w.z; a.w += s * w.w;
}
__device__ inline void f4acc(float4& a, const float4& b) {
    a.x += b.x; a.y += b.y; a.z += b.z; a.w += b.w;
}

// ---------------- K1: blocks 0..59: h1 = relu(f@W1+b1), h2 slice; block 60: A_hat ----------------
__global__ void k1_h2(const float* __restrict__ f, const float* __restrict__ W1,
                      const float* __restrict__ b1, const float* __restrict__ W2,
                      const float* __restrict__ b2, const int* __restrict__ edges,
                      float* __restrict__ ws) {
    int tid = threadIdx.x;
    if (blockIdx.x == 60) {
        // build A_hat = D^-1/2 (A+I) D^-1/2  (15x15 dense)
        __shared__ float dinv[NN];
        __shared__ float A[NN * NN];
        if (tid < NN) {
            int deg = 1;  // self loop
            for (int i = 0; i < NE; ++i) deg += (edges[NE + i] == tid) ? 1 : 0;
            dinv[tid] = rsqrtf((float)deg);
        }
        __syncthreads();
        if (tid < NN * NN) {
            int r = tid / NN, c = tid % NN;
            A[tid] = (r == c) ? dinv[r] * dinv[r] : 0.0f;
        }
        __syncthreads();
        if (tid == 0) {
            for (int i = 0; i < NE; ++i) {
                int s = edges[i], d = edges[NE + i];
                A[d * NN + s] += dinv[s] * dinv[d];
            }
        }
        __syncthreads();
        if (tid < NN * NN) ws[OFF_A + tid] = A[tid];
        return;
    }
    __shared__ float h1[H1_DIM];
    __shared__ float4 red[32][8];
    float fr[NN];
#pragma unroll
    for (int k = 0; k < NN; ++k) fr[k] = f[k];
    for (int j = tid; j < H1_DIM; j += 256) {
        float acc = b1[j];
#pragma unroll
        for (int k = 0; k < NN; ++k) acc += fr[k] * W1[k * H1_DIM + j];
        h1[j] = fmaxf(acc, 0.0f);
    }
    __syncthreads();
    int jg = tid & 7, kc = tid >> 3;            // 8 f4-groups (32 outputs), 32 k-chunks of 15
    int j = blockIdx.x * 32 + jg * 4;
    float4 acc = make_float4(0.f, 0.f, 0.f, 0.f);
    for (int r = 0; r < 15; ++r) {
        int k = kc * 15 + r;
        float4 w = *(const float4*)(W2 + k * H2_DIM + j);
        f4ma(acc, h1[k], w);
    }
    red[kc][jg] = acc;
    __syncthreads();
    for (int s = 16; s >= 1; s >>= 1) {
        if (kc < s) f4acc(red[kc][jg], red[kc + s][jg]);
        __syncthreads();
    }
    if (kc == 0) {
        float4 b = *(const float4*)(b2 + j);
        float4 v = red[0][jg];
        v.x = fmaxf(v.x + b.x, 0.f); v.y = fmaxf(v.y + b.y, 0.f);
        v.z = fmaxf(v.z + b.z, 0.f); v.w = fmaxf(v.w + b.w, 0.f);
        *(float4*)(ws + OFF_H2 + j) = v;
    }
}

// ---------------- K2: h3 partials = h2 @ W3 (~118 MB stream via relu-zero row skip) ----------------
// grid (32 col-blocks of 960, 16 k-chunks of 120 rows) = 512 blocks = EXACTLY 2/CU (no imbalance)
// block 256: lanes 0..239 each own one float4 column for all rows. Nontemporal W3 stream.
__global__ void k2_h3(const float* __restrict__ W3, float* __restrict__ ws) {
    __shared__ float cval[120];
    __shared__ int   coff[120];
    __shared__ int   wcnt[2];
    int tid = threadIdx.x;
    int cb = blockIdx.x, kc = blockIdx.y;
    int kbase = kc * 120;
    float hv = 0.0f;
    if (tid < 120) hv = ws[OFF_H2 + kbase + tid];
    int lane = tid & 63, wv = tid >> 6;
    bool act = (tid < 120) && (hv != 0.0f);
    unsigned long long m = __ballot(act);
    if (wv < 2 && lane == 0) wcnt[wv] = __popcll(m);
    __syncthreads();
    if (act) {
        int off = (wv == 1) ? wcnt[0] : 0;
        int p = off + __popcll(m & ((1ull << lane) - 1ull));
        coff[p] = (kbase + tid) * H3_DIM;
        cval[p] = hv;
    }
    __syncthreads();
    int nr = wcnt[0] + wcnt[1];
    if (tid >= 240) return;                     // no barriers after this point
    int col = cb * 960 + tid * 4;
    float4 acc = make_float4(0.f, 0.f, 0.f, 0.f);
#pragma unroll 8
    for (int r = 0; r < nr; ++r) {
        vf4 w = __builtin_nontemporal_load((const vf4*)(W3 + (size_t)coff[r] + col));
        float s = cval[r];
        acc.x += s * w.x; acc.y += s * w.y; acc.z += s * w.z; acc.w += s * w.w;
    }
    *(float4*)(ws + OFF_P3 + (size_t)kc * H3_DIM + col) = acc;
}

// ---------------- K34: fused (h3 = sum16 P3 + b3; Xg1 = A_hat@h3) + Xg1 @ gW1 -> P1 partials ----
// grid (1024/128 = 8, 2048/128 = 16); block 256 = 32 f4-groups x 8 k-subgroups
__global__ void k34_mm1(const float* __restrict__ b3, const float* __restrict__ gW1,
                        float* __restrict__ ws) {
    __shared__ float4 red[8][32][NN];           // 61440 B; S aliases here pre-MAC
    __shared__ float Al[NN * NN];
    __shared__ float Xl[NN * 128];
    float* S = (float*)red;                     // 15*128 floats (fits)
    int tid = threadIdx.x;
    int e0 = blockIdx.y * 128;
    for (int i = tid; i < NN * NN; i += 256) Al[i] = ws[OFF_A + i];
    for (int q = tid; q < NN * 128; q += 256) {
        int mm = q >> 7, c = q & 127;
        int j = mm * EMBED + e0 + c;
        float s = b3[j];
#pragma unroll
        for (int p = 0; p < 16; ++p) s += ws[OFF_P3 + p * H3_DIM + j];
        S[q] = s;
    }
    __syncthreads();
    for (int q = tid; q < NN * 128; q += 256) {
        int n = q >> 7, c = q & 127;
        float x = 0.f;
#pragma unroll
        for (int mm = 0; mm < NN; ++mm) x += Al[n * NN + mm] * S[mm * 128 + c];
        Xl[q] = x;
    }
    __syncthreads();                             // S (red alias) dead after this
    int fg = tid & 31, kt = tid >> 5;
    int f = blockIdx.x * 128 + fg * 4;
    float4 acc[NN];
#pragma unroll
    for (int n = 0; n < NN; ++n) acc[n] = make_float4(0.f, 0.f, 0.f, 0.f);
    for (int r = 0; r < 16; ++r) {
        int e = kt * 16 + r;
        float4 w = *(const float4*)(gW1 + (size_t)(e0 + e) * F1D + f);
#pragma unroll
        for (int n = 0; n < NN; ++n) f4ma(acc[n], Xl[n * 128 + e], w);
    }
    __syncthreads();
#pragma unroll
    for (int n = 0; n < NN; ++n) red[kt][fg][n] = acc[n];
    __syncthreads();
    for (int s = 4; s >= 1; s >>= 1) {
        if (kt < s) {
#pragma unroll
            for (int n = 0; n < NN; ++n) f4acc(red[kt][fg][n], red[kt + s][fg][n]);
        }
        __syncthreads();
    }
    if (kt == 0) {
#pragma unroll
        for (int n = 0; n < NN; ++n)
            *(float4*)(ws + OFF_P1 + (size_t)blockIdx.y * NN * F1D + n * F1D + f) = red[0][fg][n];
    }
}

// ---------------- K56: fused (X1 = relu(sum16 P1+gb1); Xg2 = A_hat@X1) + Xg2 @ gW2 -> P2 ----------
// grid (512/128 = 4, 1024/64 = 16); block 256 = 32 f4-groups x 8 k-subgroups
__global__ void k56_mm2(const float* __restrict__ gb1, const float* __restrict__ gW2,
                        float* __restrict__ ws) {
    __shared__ float4 red[8][32][NN];           // 61440 B; S aliases here pre-MAC
    __shared__ float Al[NN * NN];
    __shared__ float Xl[NN * 64];
    float* S = (float*)red;                     // 15*64 floats
    int tid = threadIdx.x;
    int e0 = blockIdx.y * 64;
    for (int i = tid; i < NN * NN; i += 256) Al[i] = ws[OFF_A + i];
    for (int q = tid; q < NN * 64; q += 256) {
        int mm = q >> 6, c = q & 63;
        float s = gb1[e0 + c];
#pragma unroll
        for (int p = 0; p < 16; ++p) s += ws[OFF_P1 + p * (NN * F1D) + mm * F1D + e0 + c];
        S[q] = fmaxf(s, 0.f);
    }
    __syncthreads();
    for (int q = tid; q < NN * 64; q += 256) {
        int n = q >> 6, c = q & 63;
        float x = 0.f;
#pragma unroll
        for (int mm = 0; mm < NN; ++mm) x += Al[n * NN + mm] * S[mm * 64 + c];
        Xl[q] = x;
    }
    __syncthreads();                             // S (red alias) dead after this
    int fg = tid & 31, kt = tid >> 5;
    int f = blockIdx.x * 128 + fg * 4;
    float4 acc[NN];
#pragma unroll
    for (int n = 0; n < NN; ++n) acc[n] = make_float4(0.f, 0.f, 0.f, 0.f);
    for (int r = 0; r < 8; ++r) {
        int e = kt * 8 + r;
        float4 w = *(const float4*)(gW2 + (size_t)(e0 + e) * F2D + f);
#pragma unroll
        for (int n = 0; n < NN; ++n) f4ma(acc[n], Xl[n * 64 + e], w);
    }
    __syncthreads();
#pragma unroll
    for (int n = 0; n < NN; ++n) red[kt][fg][n] = acc[n];
    __syncthreads();
    for (int s = 4; s >= 1; s >>= 1) {
        if (kt < s) {
#pragma unroll
            for (int n = 0; n < NN; ++n) f4acc(red[kt][fg][n], red[kt + s][fg][n]);
        }
        __syncthreads();
    }
    if (kt == 0) {
#pragma unroll
        for (int n = 0; n < NN; ++n)
            *(float4*)(ws + OFF_P2 + (size_t)blockIdx.y * NN * F2D + n * F2D + f) = red[0][fg][n];
    }
}

// ---------------- K78: fused X2/xbar/ctx. grid 32 blocks x 16 ctx outputs ----------------
// Each block recomputes X2 = sum16 P2 + gb2 (L2-resident, 491 KB) and xbar; block 0 writes X2.
__global__ void k78_ctx(const float* __restrict__ gb2, const float* __restrict__ attW,
                        float* __restrict__ ws) {
    __shared__ float S[NN * F2D];               // 30720 B
    __shared__ float xb[F2D];
    __shared__ float4 red[64][4];
    int tid = threadIdx.x;
    for (int q = tid; q < NN * F2D; q += 256) {
        float s = gb2[q & 511];
#pragma unroll
        for (int p = 0; p < 16; ++p) s += ws[OFF_P2 + p * (NN * F2D) + q];
        S[q] = s;
        if (blockIdx.x == 0) ws[OFF_X2 + q] = s;
    }
    __syncthreads();
    for (int c = tid; c < F2D; c += 256) {
        float s = 0.f;
#pragma unroll
        for (int n = 0; n < NN; ++n) s += S[n * F2D + c];
        xb[c] = s * (1.0f / 15.0f);
    }
    __syncthreads();
    int fg = tid & 3, kt = tid >> 2;            // 4 f4-groups (16 outputs), 64 k-chunks of 8
    int f = blockIdx.x * 16 + fg * 4;
    float4 acc = make_float4(0.f, 0.f, 0.f, 0.f);
    for (int r = 0; r < 8; ++r) {
        int e = kt * 8 + r;
        float4 w = *(const float4*)(attW + e * F2D + f);
        f4ma(acc, xb[e], w);
    }
    red[kt][fg] = acc;
    __syncthreads();
    for (int s = 32; s >= 1; s >>= 1) {
        if (kt < s) f4acc(red[kt][fg], red[kt + s][fg]);
        __syncthreads();
    }
    if (kt == 0) {
        float4 v = red[0][fg];
        ws[OFF_CTX + f + 0] = tanhf(v.x);
        ws[OFF_CTX + f + 1] = tanhf(v.y);
        ws[OFF_CTX + f + 2] = tanhf(v.z);
        ws[OFF_CTX + f + 3] = tanhf(v.w);
    }
}

// ---------------- K9: scores, rep, logits, softmax/loss ----------------
__global__ void k9_final(const float* __restrict__ fcW, const float* __restrict__ fcb,
                         const float* __restrict__ target, const float* __restrict__ ws,
                         float* __restrict__ out) {
    __shared__ float x2l[NN * F2D];
    __shared__ float ctxl[F2D];
    __shared__ float scores[16];
    __shared__ float rep[F2D];
    __shared__ float logits[3];
    int tid = threadIdx.x;
    for (int i = tid; i < NN * F2D; i += 256) x2l[i] = ws[OFF_X2 + i];
    for (int i = tid; i < F2D; i += 256) ctxl[i] = ws[OFF_CTX + i];
    __syncthreads();
    {
        int g = tid >> 4, l = tid & 15;
        if (g < NN) {
            float p = 0.f;
            for (int i = 0; i < 32; ++i) {
                int e = l + 16 * i;
                p += x2l[g * F2D + e] * ctxl[e];
            }
            p += __shfl_xor(p, 1); p += __shfl_xor(p, 2);
            p += __shfl_xor(p, 4); p += __shfl_xor(p, 8);
            if (l == 0) scores[g] = 1.0f / (1.0f + expf(-p));
        }
    }
    __syncthreads();
    for (int fi = tid; fi < F2D; fi += 256) {
        float v = 0.f;
#pragma unroll
        for (int n = 0; n < NN; ++n) v += x2l[n * F2D + fi] * scores[n];
        rep[fi] = v;
    }
    __syncthreads();
    if (tid < 192) {
        int j = tid >> 6, l = tid & 63;
        float p = 0.f;
        for (int i = 0; i < 8; ++i) {
            int e = l + 64 * i;
            p += rep[e] * fcW[e * 3 + j];
        }
        p += __shfl_xor(p, 1); p += __shfl_xor(p, 2); p += __shfl_xor(p, 4);
        p += __shfl_xor(p, 8); p += __shfl_xor(p, 16); p += __shfl_xor(p, 32);
        if (l == 0) logits[j] = p + fcb[j];
    }
    __syncthreads();
    if (tid == 0) {
        float t0 = target[0], t1 = target[1], t2 = target[2];
        int cls = 0; float best = t0;
        if (t1 > best) { best = t1; cls = 1; }
        if (t2 > best) { cls = 2; }
        float l0 = logits[0], l1 = logits[1], l2 = logits[2];
        float m = fmaxf(l0, fmaxf(l1, l2));
        float e0 = expf(l0 - m), e1 = expf(l1 - m), e2 = expf(l2 - m);
        float s = e0 + e1 + e2;
        float lc = (cls == 0) ? l0 : ((cls == 1) ? l1 : l2);
        out[0] = -(lc - m - logf(s));
        out[1] = e0 / s; out[2] = e1 / s; out[3] = e2 / s;
    }
}

extern "C" void kernel_launch(void* const* d_in, const int* in_sizes, int n_in,
                              void* d_out, int out_size, void* d_ws, size_t ws_size,
                              hipStream_t stream) {
    const float* f    = (const float*)d_in[0];
    const int*   ei   = (const int*)d_in[1];
    const float* tgt  = (const float*)d_in[2];
    const float* W1   = (const float*)d_in[3];
    const float* b1   = (const float*)d_in[4];
    const float* W2   = (const float*)d_in[5];
    const float* b2   = (const float*)d_in[6];
    const float* W3   = (const float*)d_in[7];
    const float* b3   = (const float*)d_in[8];
    const float* gW1  = (const float*)d_in[9];
    const float* gb1  = (const float*)d_in[10];
    const float* gW2  = (const float*)d_in[11];
    const float* gb2  = (const float*)d_in[12];
    const float* attW = (const float*)d_in[13];
    const float* fcW  = (const float*)d_in[14];
    const float* fcb  = (const float*)d_in[15];
    float* ws  = (float*)d_ws;
    float* out = (float*)d_out;

    k1_h2<<<dim3(61), dim3(256), 0, stream>>>(f, W1, b1, W2, b2, ei, ws);
    k2_h3<<<dim3(32, 16), dim3(256), 0, stream>>>(W3, ws);
    k34_mm1<<<dim3(8, 16), dim3(256), 0, stream>>>(b3, gW1, ws);
    k56_mm2<<<dim3(4, 16), dim3(256), 0, stream>>>(gb1, gW2, ws);
    k78_ctx<<<dim3(32), dim3(256), 0, stream>>>(gb2, attW, ws);
    k9_final<<<dim3(1), dim3(256), 0, stream>>>(fcW, fcb, tgt, ws, out);
}

// Round 6
// 374.638 us; speedup vs baseline: 1.8047x; 1.0152x over previous
//
#include <hip/hip_runtime.h>
#include <math.h>

#define NN 15          // nodes
#define EMBED 2048
#define F1D 1024
#define F2D 512
#define NE 120         // edges
#define H1_DIM 480
#define H2_DIM 1920
#define H3_DIM 30720   // 15*2048

// workspace layout (float offsets) — no zero-init needed anywhere
#define OFF_A    0         // 225 (pad 256)
#define OFF_H2   256       // 1920 (pad 2048) -> 2304
#define OFF_P3   2304      // 16*30720 = 491520 -> 493824   (k2 K-split partials)
#define OFF_XG1  493824    // 15*2048 = 30720 -> 524544     (A_hat @ h3)
#define OFF_P1   524544    // 16*15*1024 = 245760 -> 770304
#define OFF_XG2  770304    // 15*1024 = 15360 -> 785664     (A_hat @ relu(...))
#define OFF_P2   785664    // 16*15*512 = 122880 -> 908544
#define OFF_X2   908544    // 15*512 = 7680 -> 916224
#define OFF_XBAR 916224    // 512 -> 916736
#define OFF_CTX  916736    // 512 -> 917248

typedef float vf4 __attribute__((ext_vector_type(4)));

__device__ inline void f4ma(float4& a, float s, const float4& w) {
    a.x += s * w.x; a.y += s * w.y; a.z += s * w.z; a.w += s * w.w;
}
__device__ inline void f4acc(float4& a, const float4& b) {
    a.x += b.x; a.y += b.y; a.z += b.z; a.w += b.w;
}

// ---------------- K1: blocks 0..59: h1 = relu(f@W1+b1), h2 slice; block 60: A_hat ----------------
__global__ void k1_h2(const float* __restrict__ f, const float* __restrict__ W1,
                      const float* __restrict__ b1, const float* __restrict__ W2,
                      const float* __restrict__ b2, const int* __restrict__ edges,
                      float* __restrict__ ws) {
    int tid = threadIdx.x;
    if (blockIdx.x == 60) {
        // build A_hat = D^-1/2 (A+I) D^-1/2  (15x15 dense)
        __shared__ float dinv[NN];
        __shared__ float A[NN * NN];
        if (tid < NN) {
            int deg = 1;  // self loop
            for (int i = 0; i < NE; ++i) deg += (edges[NE + i] == tid) ? 1 : 0;
            dinv[tid] = rsqrtf((float)deg);
        }
        __syncthreads();
        if (tid < NN * NN) {
            int r = tid / NN, c = tid % NN;
            A[tid] = (r == c) ? dinv[r] * dinv[r] : 0.0f;
        }
        __syncthreads();
        if (tid == 0) {
            for (int i = 0; i < NE; ++i) {
                int s = edges[i], d = edges[NE + i];
                A[d * NN + s] += dinv[s] * dinv[d];
            }
        }
        __syncthreads();
        if (tid < NN * NN) ws[OFF_A + tid] = A[tid];
        return;
    }
    __shared__ float h1[H1_DIM];
    __shared__ float4 red[32][8];
    float fr[NN];
#pragma unroll
    for (int k = 0; k < NN; ++k) fr[k] = f[k];
    for (int j = tid; j < H1_DIM; j += 256) {
        float acc = b1[j];
#pragma unroll
        for (int k = 0; k < NN; ++k) acc += fr[k] * W1[k * H1_DIM + j];
        h1[j] = fmaxf(acc, 0.0f);
    }
    __syncthreads();
    int jg = tid & 7, kc = tid >> 3;            // 8 f4-groups (32 outputs), 32 k-chunks of 15
    int j = blockIdx.x * 32 + jg * 4;
    float4 acc = make_float4(0.f, 0.f, 0.f, 0.f);
    for (int r = 0; r < 15; ++r) {
        int k = kc * 15 + r;
        float4 w = *(const float4*)(W2 + k * H2_DIM + j);
        f4ma(acc, h1[k], w);
    }
    red[kc][jg] = acc;
    __syncthreads();
    for (int s = 16; s >= 1; s >>= 1) {
        if (kc < s) f4acc(red[kc][jg], red[kc + s][jg]);
        __syncthreads();
    }
    if (kc == 0) {
        float4 b = *(const float4*)(b2 + j);
        float4 v = red[0][jg];
        v.x = fmaxf(v.x + b.x, 0.f); v.y = fmaxf(v.y + b.y, 0.f);
        v.z = fmaxf(v.z + b.z, 0.f); v.w = fmaxf(v.w + b.w, 0.f);
        *(float4*)(ws + OFF_H2 + j) = v;
    }
}

// ---------------- K2: h3 partials = h2 @ W3 (~118 MB stream via relu-zero row skip) ----------------
// grid (32 col-blocks of 960, 16 k-chunks of 120 rows) = 512 blocks = EXACTLY 2/CU (no imbalance)
// block 256: lanes 0..239 each own one float4 column for all rows. Nontemporal W3 stream.
__global__ void k2_h3(const float* __restrict__ W3, float* __restrict__ ws) {
    __shared__ float cval[120];
    __shared__ int   coff[120];
    __shared__ int   wcnt[2];
    int tid = threadIdx.x;
    int cb = blockIdx.x, kc = blockIdx.y;
    int kbase = kc * 120;
    float hv = 0.0f;
    if (tid < 120) hv = ws[OFF_H2 + kbase + tid];
    int lane = tid & 63, wv = tid >> 6;
    bool act = (tid < 120) && (hv != 0.0f);
    unsigned long long m = __ballot(act);
    if (wv < 2 && lane == 0) wcnt[wv] = __popcll(m);
    __syncthreads();
    if (act) {
        int off = (wv == 1) ? wcnt[0] : 0;
        int p = off + __popcll(m & ((1ull << lane) - 1ull));
        coff[p] = (kbase + tid) * H3_DIM;
        cval[p] = hv;
    }
    __syncthreads();
    int nr = wcnt[0] + wcnt[1];
    if (tid >= 240) return;                     // no barriers after this point
    int col = cb * 960 + tid * 4;
    float4 acc = make_float4(0.f, 0.f, 0.f, 0.f);
#pragma unroll 8
    for (int r = 0; r < nr; ++r) {
        vf4 w = __builtin_nontemporal_load((const vf4*)(W3 + (size_t)coff[r] + col));
        float s = cval[r];
        acc.x += s * w.x; acc.y += s * w.y; acc.z += s * w.z; acc.w += s * w.w;
    }
    *(float4*)(ws + OFF_P3 + (size_t)kc * H3_DIM + col) = acc;
}

// ---------------- K3: h3 = sum 16 partials + b3; Xg1 = A_hat @ h3  [15,2048] ----------------
// grid 64 blocks x 32 cols
__global__ void k3_agg1(const float* __restrict__ b3, float* __restrict__ ws) {
    __shared__ float Al[NN * NN];
    __shared__ float S[NN][32];
    int tid = threadIdx.x;
    int c0 = blockIdx.x * 32;
    for (int i = tid; i < NN * NN; i += 256) Al[i] = ws[OFF_A + i];
    for (int q = tid; q < NN * 32; q += 256) {
        int m = q >> 5, c = q & 31;
        int j = m * EMBED + c0 + c;
        float s = b3[j];
#pragma unroll
        for (int p = 0; p < 16; ++p) s += ws[OFF_P3 + p * H3_DIM + j];
        S[m][c] = s;
    }
    __syncthreads();
    for (int q = tid; q < NN * 32; q += 256) {
        int n = q >> 5, c = q & 31;
        float x = 0.f;
#pragma unroll
        for (int m = 0; m < NN; ++m) x += Al[n * NN + m] * S[m][c];
        ws[OFF_XG1 + n * EMBED + c0 + c] = x;
    }
}

// ---------------- generic [15,IN] @ [IN,OUT] -> K-split partials (no atomics) ----------------
// grid (OUT/128, IN/ECH); block 256 = 32 f4-groups x 8 k-subgroups; P[p][n][f], p = blockIdx.y
template<int IN, int OUT, int ECH>
__global__ void k_mmP(const float* __restrict__ X, const float* __restrict__ W,
                      float* __restrict__ P) {
    __shared__ float Xl[NN * ECH];
    __shared__ float4 red[8][32][NN];           // 61440 B
    int tid = threadIdx.x;
    int e0 = blockIdx.y * ECH;
    for (int i = tid; i < NN * ECH; i += 256) {
        int n = i / ECH, e = i - n * ECH;
        Xl[i] = X[n * IN + e0 + e];
    }
    __syncthreads();
    int fg = tid & 31, kt = tid >> 5;
    int f = blockIdx.x * 128 + fg * 4;
    float4 acc[NN];
#pragma unroll
    for (int n = 0; n < NN; ++n) acc[n] = make_float4(0.f, 0.f, 0.f, 0.f);
    const int RPT = ECH / 8;
    for (int r = 0; r < RPT; ++r) {
        int e = kt * RPT + r;
        float4 w = *(const float4*)(W + (size_t)(e0 + e) * OUT + f);
#pragma unroll
        for (int n = 0; n < NN; ++n) f4ma(acc[n], Xl[n * ECH + e], w);
    }
    __syncthreads();
#pragma unroll
    for (int n = 0; n < NN; ++n) red[kt][fg][n] = acc[n];
    __syncthreads();
    for (int s = 4; s >= 1; s >>= 1) {
        if (kt < s) {
#pragma unroll
            for (int n = 0; n < NN; ++n) f4acc(red[kt][fg][n], red[kt + s][fg][n]);
        }
        __syncthreads();
    }
    if (kt == 0) {
#pragma unroll
        for (int n = 0; n < NN; ++n) {
            float4 v = red[0][fg][n];
            *(float4*)(P + (size_t)blockIdx.y * NN * OUT + n * OUT + f) = v;
        }
    }
}

// ---------------- K5: X1 = relu(sum P1 + gb1); Xg2 = A_hat @ X1  [15,1024] ----------------
// grid 16 blocks x 64 cols
__global__ void k5_fin1(const float* __restrict__ gb1, float* __restrict__ ws) {
    __shared__ float Al[NN * NN];
    __shared__ float S[NN][64];
    int tid = threadIdx.x;
    int f0 = blockIdx.x * 64;
    for (int i = tid; i < NN * NN; i += 256) Al[i] = ws[OFF_A + i];
    for (int q = tid; q < NN * 64; q += 256) {
        int n = q >> 6, c = q & 63;
        float s = gb1[f0 + c];
#pragma unroll
        for (int p = 0; p < 16; ++p) s += ws[OFF_P1 + p * (NN * F1D) + n * F1D + f0 + c];
        S[n][c] = fmaxf(s, 0.f);
    }
    __syncthreads();
    for (int q = tid; q < NN * 64; q += 256) {
        int n = q >> 6, c = q & 63;
        float x = 0.f;
#pragma unroll
        for (int m = 0; m < NN; ++m) x += Al[n * NN + m] * S[m][c];
        ws[OFF_XG2 + n * F1D + f0 + c] = x;
    }
}

// ---------------- K7: X2 = sum P2 + gb2 (no relu); xbar = mean_n X2 ----------------
// grid 8 blocks x 64 cols
__global__ void k7_fin2(const float* __restrict__ gb2, float* __restrict__ ws) {
    __shared__ float S[NN][64];
    int tid = threadIdx.x;
    int f0 = blockIdx.x * 64;
    for (int q = tid; q < NN * 64; q += 256) {
        int n = q >> 6, c = q & 63;
        float s = gb2[f0 + c];
#pragma unroll
        for (int p = 0; p < 16; ++p) s += ws[OFF_P2 + p * (NN * F2D) + n * F2D + f0 + c];
        S[n][c] = s;
        ws[OFF_X2 + n * F2D + f0 + c] = s;
    }
    __syncthreads();
    if (tid < 64) {
        float s = 0.f;
#pragma unroll
        for (int n = 0; n < NN; ++n) s += S[n][tid];
        ws[OFF_XBAR + f0 + tid] = s * (1.0f / 15.0f);
    }
}

// ---------------- K8: ctx = tanh(xbar @ attW) ----------------
// grid 32 blocks, each 16 ctx outputs
__global__ void k8_ctx(const float* __restrict__ attW, float* __restrict__ ws) {
    __shared__ float xb[F2D];
    __shared__ float4 red[64][4];
    int tid = threadIdx.x;
    for (int e = tid; e < F2D; e += 256) xb[e] = ws[OFF_XBAR + e];
    __syncthreads();
    int fg = tid & 3, kt = tid >> 2;            // 4 f4-groups (16 outputs), 64 k-chunks of 8
    int f = blockIdx.x * 16 + fg * 4;
    float4 acc = make_float4(0.f, 0.f, 0.f, 0.f);
    for (int r = 0; r < 8; ++r) {
        int e = kt * 8 + r;
        float4 w = *(const float4*)(attW + e * F2D + f);
        f4ma(acc, xb[e], w);
    }
    red[kt][fg] = acc;
    __syncthreads();
    for (int s = 32; s >= 1; s >>= 1) {
        if (kt < s) f4acc(red[kt][fg], red[kt + s][fg]);
        __syncthreads();
    }
    if (kt == 0) {
        float4 v = red[0][fg];
        ws[OFF_CTX + f + 0] = tanhf(v.x);
        ws[OFF_CTX + f + 1] = tanhf(v.y);
        ws[OFF_CTX + f + 2] = tanhf(v.z);
        ws[OFF_CTX + f + 3] = tanhf(v.w);
    }
}

// ---------------- K9: scores, rep, logits, softmax/loss ----------------
__global__ void k9_final(const float* __restrict__ fcW, const float* __restrict__ fcb,
                         const float* __restrict__ target, const float* __restrict__ ws,
                         float* __restrict__ out) {
    __shared__ float x2l[NN * F2D];
    __shared__ float ctxl[F2D];
    __shared__ float scores[16];
    __shared__ float rep[F2D];
    __shared__ float logits[3];
    int tid = threadIdx.x;
    for (int i = tid; i < NN * F2D; i += 256) x2l[i] = ws[OFF_X2 + i];
    for (int i = tid; i < F2D; i += 256) ctxl[i] = ws[OFF_CTX + i];
    __syncthreads();
    {
        int g = tid >> 4, l = tid & 15;
        if (g < NN) {
            float p = 0.f;
            for (int i = 0; i < 32; ++i) {
                int e = l + 16 * i;
                p += x2l[g * F2D + e] * ctxl[e];
            }
            p += __shfl_xor(p, 1); p += __shfl_xor(p, 2);
            p += __shfl_xor(p, 4); p += __shfl_xor(p, 8);
            if (l == 0) scores[g] = 1.0f / (1.0f + expf(-p));
        }
    }
    __syncthreads();
    for (int fi = tid; fi < F2D; fi += 256) {
        float v = 0.f;
#pragma unroll
        for (int n = 0; n < NN; ++n) v += x2l[n * F2D + fi] * scores[n];
        rep[fi] = v;
    }
    __syncthreads();
    if (tid < 192) {
        int j = tid >> 6, l = tid & 63;
        float p = 0.f;
        for (int i = 0; i < 8; ++i) {
            int e = l + 64 * i;
            p += rep[e] * fcW[e * 3 + j];
        }
        p += __shfl_xor(p, 1); p += __shfl_xor(p, 2); p += __shfl_xor(p, 4);
        p += __shfl_xor(p, 8); p += __shfl_xor(p, 16); p += __shfl_xor(p, 32);
        if (l == 0) logits[j] = p + fcb[j];
    }
    __syncthreads();
    if (tid == 0) {
        float t0 = target[0], t1 = target[1], t2 = target[2];
        int cls = 0; float best = t0;
        if (t1 > best) { best = t1; cls = 1; }
        if (t2 > best) { cls = 2; }
        float l0 = logits[0], l1 = logits[1], l2 = logits[2];
        float m = fmaxf(l0, fmaxf(l1, l2));
        float e0 = expf(l0 - m), e1 = expf(l1 - m), e2 = expf(l2 - m);
        float s = e0 + e1 + e2;
        float lc = (cls == 0) ? l0 : ((cls == 1) ? l1 : l2);
        out[0] = -(lc - m - logf(s));
        out[1] = e0 / s; out[2] = e1 / s; out[3] = e2 / s;
    }
}

extern "C" void kernel_launch(void* const* d_in, const int* in_sizes, int n_in,
                              void* d_out, int out_size, void* d_ws, size_t ws_size,
                              hipStream_t stream) {
    const float* f    = (const float*)d_in[0];
    const int*   ei   = (const int*)d_in[1];
    const float* tgt  = (const float*)d_in[2];
    const float* W1   = (const float*)d_in[3];
    const float* b1   = (const float*)d_in[4];
    const float* W2   = (const float*)d_in[5];
    const float* b2   = (const float*)d_in[6];
    const float* W3   = (const float*)d_in[7];
    const float* b3   = (const float*)d_in[8];
    const float* gW1  = (const float*)d_in[9];
    const float* gb1  = (const float*)d_in[10];
    const float* gW2  = (const float*)d_in[11];
    const float* gb2  = (const float*)d_in[12];
    const float* attW = (const float*)d_in[13];
    const float* fcW  = (const float*)d_in[14];
    const float* fcb  = (const float*)d_in[15];
    float* ws  = (float*)d_ws;
    float* out = (float*)d_out;

    k1_h2<<<dim3(61), dim3(256), 0, stream>>>(f, W1, b1, W2, b2, ei, ws);
    k2_h3<<<dim3(32, 16), dim3(256), 0, stream>>>(W3, ws);
    k3_agg1<<<dim3(64), dim3(256), 0, stream>>>(b3, ws);
    k_mmP<2048, 1024, 128><<<dim3(8, 16), dim3(256), 0, stream>>>(ws + OFF_XG1, gW1, ws + OFF_P1);
    k5_fin1<<<dim3(16), dim3(256), 0, stream>>>(gb1, ws);
    k_mmP<1024, 512, 64><<<dim3(4, 16), dim3(256), 0, stream>>>(ws + OFF_XG2, gW2, ws + OFF_P2);
    k7_fin2<<<dim3(8), dim3(256), 0, stream>>>(gb2, ws);
    k8_ctx<<<dim3(32), dim3(256), 0, stream>>>(attW, ws);
    k9_final<<<dim3(1), dim3(256), 0, stream>>>(fcW, fcb, tgt, ws, out);
}